// Round 2
// baseline (69.508 us; speedup 1.0000x reference)
//
#include <hip/hip_runtime.h>

#define B_SIZE 4096
#define IN_F   8192
#define OUT_W  8194           // IN_F + 2 after slicing off the 2-pads
#define ROWS   32             // rows per block
#define CHUNKS 8              // column chunks (grid.x), 1024 cols each

typedef float f32x4 __attribute__((ext_vector_type(4)));
typedef float f32x2 __attribute__((ext_vector_type(2)));

// ---------------------------------------------------------------------------
// Fused 3-tap banded correlation:
//   out[b][j] = W[j+2,j]*x[b][j] + W[j+2,j+1]*x[b][j+1] + W[j+2,j+2]*x[b][j+2]
//               + count(j+2)*bias[j+2]          (taps with n>=IN_F dropped)
//   out[b][8192..8193] = 0  (no valid taps, count=0)
//
// Each thread owns 4 consecutive output columns; gathers its 12 W-taps + 4
// bias terms ONCE per 32-row strip (W band lines ~3MB, L2/L3-resident across
// the 128 grid.y repeats). Row loop: one float4 x-load; halo x[j+4],x[j+5]
// comes from lane t+1 via __shfl_down (lane 63: guarded scalar fallback).
// Stores as 2x float2 (row byte stride 32776 ≡ 8 mod 16, float4 illegal on
// odd rows; 64 lanes x 8B contiguous coalesces perfectly either way).
// ---------------------------------------------------------------------------
__global__ __launch_bounds__(256) void glia_band_kernel(
    const float* __restrict__ x, const float* __restrict__ w,
    const float* __restrict__ bias, float* __restrict__ out) {
  const int t = threadIdx.x;
  const int j = (blockIdx.x * 256 + t) * 4;          // [0, 8192) step 4

  // --- per-thread coefficient gather (once per block) ---
  float k[4][4];
#pragma unroll
  for (int q = 0; q < 4; ++q) {
    const int jj = j + q;                            // jj <= 8191
    const size_t c = (size_t)jj + 2;                 // c <= 8193 < 8198
    float c1 = 0.f, c2 = 0.f, cnt = 1.f;
    const float c0 = w[c * IN_F + jj];               // jj always valid
    if (jj + 1 < IN_F) { c1 = w[c * IN_F + jj + 1]; cnt += 1.f; }
    if (jj + 2 < IN_F) { c2 = w[c * IN_F + jj + 2]; cnt += 1.f; }
    k[q][0] = c0; k[q][1] = c1; k[q][2] = c2; k[q][3] = cnt * bias[c];
  }

  const int lane = t & 63;
  const bool last_lane = (lane == 63);
  const bool g4 = (j + 4 < IN_F);                    // false only for j=8188
  const bool g5 = (j + 5 < IN_F);
  const bool tail = (blockIdx.x == CHUNKS - 1) && (t == 255);
  const int row0 = blockIdx.y * ROWS;

#pragma unroll 4
  for (int r = 0; r < ROWS; ++r) {
    const size_t row = (size_t)(row0 + r);
    const float* xr = x + row * (size_t)IN_F;
    const f32x4 xv = *reinterpret_cast<const f32x4*>(xr + j);  // 16B aligned
    // halo: x[j+4], x[j+5] live in lane t+1's xv.x, xv.y
    float x4 = __shfl_down(xv.x, 1);
    float x5 = __shfl_down(xv.y, 1);
    if (last_lane) {                                 // cross-wave boundary
      x4 = g4 ? xr[j + 4] : 0.f;
      x5 = g5 ? xr[j + 5] : 0.f;
    }
    const float o0 = fmaf(k[0][0], xv.x, fmaf(k[0][1], xv.y, fmaf(k[0][2], xv.z, k[0][3])));
    const float o1 = fmaf(k[1][0], xv.y, fmaf(k[1][1], xv.z, fmaf(k[1][2], xv.w, k[1][3])));
    const float o2 = fmaf(k[2][0], xv.z, fmaf(k[2][1], xv.w, fmaf(k[2][2], x4,   k[2][3])));
    const float o3 = fmaf(k[3][0], xv.w, fmaf(k[3][1], x4,   fmaf(k[3][2], x5,   k[3][3])));
    float* orow = out + row * (size_t)OUT_W + j;
    *reinterpret_cast<f32x2*>(orow)     = (f32x2){o0, o1};
    *reinterpret_cast<f32x2*>(orow + 2) = (f32x2){o2, o3};
    if (tail)                                        // columns 8192..8193 = 0
      *reinterpret_cast<f32x2*>(out + row * (size_t)OUT_W + IN_F) = (f32x2){0.f, 0.f};
  }
}

extern "C" void kernel_launch(void* const* d_in, const int* in_sizes, int n_in,
                              void* d_out, int out_size, void* d_ws, size_t ws_size,
                              hipStream_t stream) {
  const float* x    = (const float*)d_in[0];   // [4096, 8192]
  const float* w    = (const float*)d_in[1];   // [8198, 8192]
  const float* bias = (const float*)d_in[2];   // [8198]
  float* out = (float*)d_out;                  // [4096, 8194]

  dim3 grid(CHUNKS, B_SIZE / ROWS);            // 8 x 128 = 1024 blocks
  glia_band_kernel<<<grid, 256, 0, stream>>>(x, w, bias, out);
}

// Round 3
// 53.221 us; speedup vs baseline: 1.3060x; 1.3060x over previous
//
#include <hip/hip_runtime.h>

#define B_SIZE 4096
#define IN_F   8192
#define OUT_W  8194           // IN_F + 2 after slicing off the 2-pads
#define ROWS   16             // rows per block (R1 geometry)
#define CHUNKS 8              // column chunks (grid.x), 1024 cols each

typedef float f32x4 __attribute__((ext_vector_type(4)));
typedef float f32x2 __attribute__((ext_vector_type(2)));

// ---------------------------------------------------------------------------
// Kernel 1: gather band coeffs, 4 threads per output column j in [0, IN_F):
//   d=0..2: coeff[j][d] = W[j+2, j+d]  (0 if j+d >= IN_F)
//   d=3   : coeff[j][3] = count(j+2) * bias[j+2]
// One load per thread, 32K threads across 512 blocks -> all ~25K scattered
// W cachelines fetched in one HBM latency round (~1-2 us) instead of R1's
// 33-block serialized gather.
// ---------------------------------------------------------------------------
__global__ __launch_bounds__(64) void coeff_kernel(
    const float* __restrict__ w, const float* __restrict__ bias,
    float* __restrict__ coeff) {
  const int gid = blockIdx.x * 64 + threadIdx.x;   // [0, 4*IN_F)
  const int j = gid >> 2;
  const int d = gid & 3;
  const size_t c = (size_t)j + 2;
  float v;
  if (d == 3) {
    const float cnt = 1.f + (j + 1 < IN_F ? 1.f : 0.f) + (j + 2 < IN_F ? 1.f : 0.f);
    v = cnt * bias[c];
  } else {
    v = (j + d < IN_F) ? w[c * IN_F + j + d] : 0.f;
  }
  coeff[4 * (size_t)j + d] = v;
}

// ---------------------------------------------------------------------------
// Kernel 2: streaming 3-tap band apply (R1 structure).
//   thread owns 4 consecutive columns; coeffs in registers; per row:
//   one float4 x-load + one guarded float2 halo load (L1-hit, same lines),
//   two nontemporal float2 stores (row stride 32776 B is 8-mod-16).
// ---------------------------------------------------------------------------
__global__ __launch_bounds__(256) void band_kernel(
    const float* __restrict__ x, const float4* __restrict__ coeff,
    float* __restrict__ out) {
  const int j = (blockIdx.x * 256 + threadIdx.x) * 4;   // [0, 8192) step 4
  const float4 k0 = coeff[j];
  const float4 k1 = coeff[j + 1];
  const float4 k2 = coeff[j + 2];
  const float4 k3 = coeff[j + 3];
  const bool ghalo = (j + 4 < IN_F);       // false only for the last thread
  const bool tail = (blockIdx.x == CHUNKS - 1) && (threadIdx.x == 255);
  const int row0 = blockIdx.y * ROWS;

#pragma unroll 4
  for (int r = 0; r < ROWS; ++r) {
    const size_t row = (size_t)(row0 + r);
    const float* xr = x + row * (size_t)IN_F;
    const f32x4 xv = *reinterpret_cast<const f32x4*>(xr + j);   // 16B aligned
    const f32x2 xh = ghalo ? *reinterpret_cast<const f32x2*>(xr + j + 4)
                           : (f32x2){0.f, 0.f};                 // 8B aligned
    const float o0 = fmaf(k0.x, xv.x, fmaf(k0.y, xv.y, fmaf(k0.z, xv.z, k0.w)));
    const float o1 = fmaf(k1.x, xv.y, fmaf(k1.y, xv.z, fmaf(k1.z, xv.w, k1.w)));
    const float o2 = fmaf(k2.x, xv.z, fmaf(k2.y, xv.w, fmaf(k2.z, xh.x, k2.w)));
    const float o3 = fmaf(k3.x, xv.w, fmaf(k3.y, xh.x, fmaf(k3.z, xh.y, k3.w)));
    float* orow = out + row * (size_t)OUT_W + j;
    __builtin_nontemporal_store((f32x2){o0, o1}, reinterpret_cast<f32x2*>(orow));
    __builtin_nontemporal_store((f32x2){o2, o3}, reinterpret_cast<f32x2*>(orow + 2));
    if (tail) {                            // columns 8192..8193 are exact zeros
      __builtin_nontemporal_store((f32x2){0.f, 0.f},
          reinterpret_cast<f32x2*>(out + row * (size_t)OUT_W + IN_F));
    }
  }
}

extern "C" void kernel_launch(void* const* d_in, const int* in_sizes, int n_in,
                              void* d_out, int out_size, void* d_ws, size_t ws_size,
                              hipStream_t stream) {
  const float* x    = (const float*)d_in[0];   // [4096, 8192]
  const float* w    = (const float*)d_in[1];   // [8198, 8192]
  const float* bias = (const float*)d_in[2];   // [8198]
  float* out = (float*)d_out;                  // [4096, 8194]
  float* coeff = (float*)d_ws;                 // IN_F * 16 B = 128 KB scratch

  coeff_kernel<<<(4 * IN_F) / 64, 64, 0, stream>>>(w, bias, coeff);

  dim3 grid(CHUNKS, B_SIZE / ROWS);            // 8 x 256 = 2048 blocks
  band_kernel<<<grid, 256, 0, stream>>>(x, (const float4*)coeff, out);
}